// Round 4
// baseline (53233.130 us; speedup 1.0000x reference)
//
#include <hip/hip_runtime.h>
#include <hip/hip_bf16.h>
#include <math.h>

// ---------------------------------------------------------------------------
// HMABottleneck: B=4, C=512, H=W=16, DI=1024, K=4 dirs, N=16 states, R=32
// Round 4: round-3 naive kernels, OUTPUT AS FLOAT32 (the round-1..3 bug:
// d_out is f32 per harness contract since the reference computes in f32).
// ---------------------------------------------------------------------------

constexpr int B_  = 4;
constexpr int C_  = 512;
constexpr int DI_ = 1024;
constexpr int K_  = 4;
constexpr int N_  = 16;
constexpr int R_  = 32;
constexpr float BNS_ = 0.9999950000374997f;   // 1/sqrt(1+1e-5)

__device__ inline float geluf(float x) {
    return 0.5f * x * (1.0f + erff(x * 0.70710678118654752f));
}
__device__ inline float siluf(float x) {
    return x / (1.0f + expf(-x));
}
__device__ inline float softplusf(float x) {
    return fmaxf(x, 0.0f) + log1pf(expf(-fabsf(x)));
}

// --------------------------- LN over channels, naive: 1 thread per row -----
__global__ void n_ln_nchw(const float* __restrict__ x, const float* __restrict__ w,
                          const float* __restrict__ b, float* __restrict__ out,
                          int L, int rows, float eps) {
    int row = blockIdx.x * 256 + threadIdx.x;
    if (row >= rows) return;
    int bb = row / L, l = row % L;
    const float* xp = x + (size_t)bb * C_ * L + l;
    float mu = 0.f;
    for (int c = 0; c < C_; c++) mu += xp[(size_t)c * L];
    mu /= (float)C_;
    float v = 0.f;
    for (int c = 0; c < C_; c++) { float d = xp[(size_t)c * L] - mu; v += d * d; }
    v /= (float)C_;
    float rstd = rsqrtf(v + eps);
    float* op = out + (size_t)row * C_;
    for (int c = 0; c < C_; c++) op[c] = (xp[(size_t)c * L] - mu) * rstd * w[c] + b[c];
}

// --------------------------- naive GEMM: out = A (M,K) * Bw(N,K)^T ---------
template <int EPI>
__global__ void n_gemm_nt(const float* __restrict__ A, const float* __restrict__ Bw,
                          float* __restrict__ Cout, int M, int Nn, int Kk,
                          const float* __restrict__ Res, int L) {
    int idx = blockIdx.x * 256 + threadIdx.x;
    if (idx >= M * Nn) return;
    int n = idx % Nn, m = idx / Nn;
    const float* a  = A + (size_t)m * Kk;
    const float* bw = Bw + (size_t)n * Kk;
    float acc = 0.f;
    for (int k = 0; k < Kk; k++) acc += a[k] * bw[k];
    if (EPI == 0) {
        Cout[(size_t)m * Nn + n] = acc;
    } else {
        int bb = m / L, l = m % L;
        size_t o = ((size_t)bb * C_ + n) * L + l;
        Cout[o] = Res[o] + acc;
    }
}

// --------------------------- depthwise 3x3 (pad1) + bias + SiLU ------------
__global__ void n_dwconv_silu(const float* __restrict__ xz, const float* __restrict__ cw,
                              const float* __restrict__ cb, float* __restrict__ xm,
                              int H, int W) {
    int L = H * W;
    int idx = blockIdx.x * 256 + threadIdx.x;            // (b, l, d) d fastest
    int total = B_ * L * DI_;
    if (idx >= total) return;
    int d = idx % DI_; int t = idx / DI_; int l = t % L; int bb = t / L;
    int h = l / W, w = l % W;
    float acc = cb[d];
    const float* wp = cw + d * 9;
    for (int dy = 0; dy < 3; dy++) {
        int hh = h + dy - 1;
        if (hh < 0 || hh >= H) continue;
        for (int dx = 0; dx < 3; dx++) {
            int ww = w + dx - 1;
            if (ww < 0 || ww >= W) continue;
            acc += xz[((size_t)bb * L + hh * W + ww) * (2 * DI_) + d] * wp[dy * 3 + dx];
        }
    }
    xm[idx] = siluf(acc);
}

// map (k,l) -> source flat index in row-major (h*W+w) order
__device__ inline int dir_src(int k, int l, int H, int W, int L) {
    int ll = (k >= 2) ? (L - 1 - l) : l;
    return (k & 1) ? ((ll % H) * W + ll / H) : ll;
}

// --------------------------- naive x_dbl: one thread per (b,k,c,l) ---------
__global__ void n_xdbl(const float* __restrict__ xm, const float* __restrict__ xproj,
                       float* __restrict__ xdbl, int H, int W) {
    int L = H * W;
    int idx = blockIdx.x * 256 + threadIdx.x;            // (b,k,c,l) l fastest
    int total = B_ * K_ * 64 * L;
    if (idx >= total) return;
    int l = idx % L; int t = idx / L; int c = t % 64; t /= 64; int k = t % K_; int bb = t / K_;
    int src = dir_src(k, l, H, W, L);
    const float* xp = xm + ((size_t)bb * L + src) * DI_;
    const float* wp = xproj + ((size_t)k * 64 + c) * DI_;
    float acc = 0.f;
    for (int d = 0; d < DI_; d++) acc += xp[d] * wp[d];
    xdbl[((size_t)(bb * K_ + k) * 64 + c) * L + l] = acc;
}

// --------------------------- fused delta + selective scan + merge ----------
__global__ void k_scan_dir(const float* __restrict__ xm, const float* __restrict__ xdbl,
                           const float* __restrict__ dtw, const float* __restrict__ dtb,
                           const float* __restrict__ Alog, const float* __restrict__ Dp,
                           float* __restrict__ ybuf, int H, int W, int kdir, int accum) {
    int L = H * W;
    int idx = blockIdx.x * 256 + threadIdx.x;    // (b, d)
    int d = idx % DI_; int bb = idx / DI_;
    float wreg[R_];
    const float* wp = dtw + ((size_t)kdir * DI_ + d) * R_;
    for (int r = 0; r < R_; r++) wreg[r] = wp[r];
    float A[N_], h[N_];
    const float* al = Alog + ((size_t)kdir * DI_ + d) * N_;
    for (int n = 0; n < N_; n++) { A[n] = -expf(al[n]); h[n] = 0.f; }
    float Dv = Dp[kdir * DI_ + d];
    float bias = dtb[kdir * DI_ + d];
    const float* bc = xdbl + (size_t)(bb * K_ + kdir) * 64 * L;
    const float* xmb = xm + (size_t)bb * L * DI_ + d;
    float* yb = ybuf + (size_t)bb * L * DI_ + d;
    for (int l = 0; l < L; l++) {
        int src = dir_src(kdir, l, H, W, L);
        float u = xmb[(size_t)src * DI_];
        float acc = bias;
        for (int r = 0; r < R_; r++) acc += bc[(size_t)r * L + l] * wreg[r];
        float dl = softplusf(acc);
        float du = dl * u;
        float y = 0.f;
        for (int n = 0; n < N_; n++) {
            float Bl = bc[(size_t)(R_ + n) * L + l];
            float Cl = bc[(size_t)(R_ + N_ + n) * L + l];
            h[n] = expf(dl * A[n]) * h[n] + du * Bl;
            y += h[n] * Cl;
        }
        float outv = y + Dv * u;
        if (accum) yb[(size_t)src * DI_] += outv;
        else       yb[(size_t)src * DI_] = outv;
    }
}

// --------------------------- LN(y)*silu(z), naive: 1 thread per row --------
__global__ void n_ln_silu(const float* __restrict__ y, const float* __restrict__ xz,
                          const float* __restrict__ onw, const float* __restrict__ onb,
                          float* __restrict__ tout, int rows) {
    int row = blockIdx.x * 256 + threadIdx.x;
    if (row >= rows) return;
    const float* yp = y + (size_t)row * DI_;
    float mu = 0.f;
    for (int d = 0; d < DI_; d++) mu += yp[d];
    mu /= (float)DI_;
    float v = 0.f;
    for (int d = 0; d < DI_; d++) { float dv = yp[d] - mu; v += dv * dv; }
    v /= (float)DI_;
    float rstd = rsqrtf(v + 1e-5f);
    const float* zp = xz + (size_t)row * 2 * DI_ + DI_;
    float* tp = tout + (size_t)row * DI_;
    for (int d = 0; d < DI_; d++) {
        tp[d] = ((yp[d] - mu) * rstd * onw[d] + onb[d]) * siluf(zp[d]);
    }
}

// --------------------------- downsample: dw conv s2 + BN + GELU ------------
__global__ void k_dwconv_s2_bn_gelu(const float* __restrict__ x, const float* __restrict__ dw,
                                    const float* __restrict__ bns, const float* __restrict__ bnb,
                                    float* __restrict__ out, int Hi, int Wi) {
    int Ho = Hi / 2, Wo = Wi / 2;
    int idx = blockIdx.x * 256 + threadIdx.x;            // (b,c,ho,wo)
    int total = B_ * C_ * Ho * Wo;
    if (idx >= total) return;
    int wo = idx % Wo; int t = idx / Wo; int ho = t % Ho; t /= Ho; int c = t % C_; int bb = t / C_;
    float acc = 0.f;
    const float* xp = x + ((size_t)bb * C_ + c) * Hi * Wi;
    const float* wp = dw + c * 9;
    for (int dy = 0; dy < 3; dy++) {
        int ih = ho * 2 + dy - 1;
        if (ih < 0 || ih >= Hi) continue;
        for (int dx = 0; dx < 3; dx++) {
            int iw = wo * 2 + dx - 1;
            if (iw < 0 || iw >= Wi) continue;
            acc += xp[ih * Wi + iw] * wp[dy * 3 + dx];
        }
    }
    acc = acc * (bns[c] * BNS_) + bnb[c];
    out[idx] = geluf(acc);
}

// --------------------------- pointwise 1x1 conv + BN + GELU ----------------
__global__ void k_pwconv_bn_gelu(const float* __restrict__ x, const float* __restrict__ pw,
                                 const float* __restrict__ bns, const float* __restrict__ bnb,
                                 float* __restrict__ out, int L) {
    int idx = blockIdx.x * 256 + threadIdx.x;            // (b,co,l)
    int total = B_ * C_ * L;
    if (idx >= total) return;
    int l = idx % L; int t = idx / L; int co = t % C_; int bb = t / C_;
    const float* xp = x + (size_t)bb * C_ * L + l;
    const float* wp = pw + (size_t)co * C_;
    float acc = 0.f;
    for (int ci = 0; ci < C_; ci++) acc += xp[(size_t)ci * L] * wp[ci];
    acc = acc * (bns[co] * BNS_) + bnb[co];
    out[idx] = geluf(acc);
}

// --------------------------- naive 3x3 conv C->C pad1 + BN epilogues -------
// MODE 0: out = gelu(bn(conv))
// MODE 1: out = gelu(bn(conv) + res)
// MODE 2: of32 = gelu(bn(conv)) + res        (final output, f32!)
template <int MODE>
__global__ void n_conv3x3(const float* __restrict__ x, const float* __restrict__ wgt,
                          const float* __restrict__ bns, const float* __restrict__ bnb,
                          const float* __restrict__ res, float* __restrict__ out,
                          int H, int W) {
    int idx = blockIdx.x * 256 + threadIdx.x;            // (b,co,h,w)
    int total = B_ * C_ * H * W;
    if (idx >= total) return;
    int w = idx % W; int t = idx / W; int h = t % H; t /= H; int co = t % C_; int bb = t / C_;
    float acc = 0.f;
    const float* xb = x + (size_t)bb * C_ * H * W;
    const float* wb = wgt + (size_t)co * C_ * 9;
    for (int ci = 0; ci < C_; ci++) {
        const float* xr = xb + (size_t)ci * H * W;
        const float* wr = wb + ci * 9;
        for (int dy = 0; dy < 3; dy++) {
            int hh = h + dy - 1;
            if (hh < 0 || hh >= H) continue;
            for (int dx = 0; dx < 3; dx++) {
                int ww = w + dx - 1;
                if (ww < 0 || ww >= W) continue;
                acc += xr[hh * W + ww] * wr[dy * 3 + dx];
            }
        }
    }
    acc = acc * (bns[co] * BNS_) + bnb[co];
    size_t o = (((size_t)bb * C_ + co) * H + h) * W + w;
    if (MODE == 0) out[o] = geluf(acc);
    else if (MODE == 1) out[o] = geluf(acc + res[o]);
    else out[o] = geluf(acc) + res[o];
}

// --------------------------- bilinear up + skip add ------------------------
__global__ void k_up_add(const float* __restrict__ low, const float* __restrict__ skip,
                         float* __restrict__ out, int Hi, int Wi, int Ho, int Wo) {
    int idx = blockIdx.x * 256 + threadIdx.x;            // (b,c,ho,wo)
    int total = B_ * C_ * Ho * Wo;
    if (idx >= total) return;
    int wo = idx % Wo; int t = idx / Wo; int ho = t % Ho; t /= Ho; int c = t % C_; int bb = t / C_;
    float fy = (float)ho * (float)(Hi - 1) / (float)(Ho - 1);
    float fx = (float)wo * (float)(Wi - 1) / (float)(Wo - 1);
    int y0 = (int)floorf(fy); int y1 = min(y0 + 1, Hi - 1); float wy = fy - (float)y0;
    int x0 = (int)floorf(fx); int x1 = min(x0 + 1, Wi - 1); float wx = fx - (float)x0;
    const float* lp = low + ((size_t)bb * C_ + c) * Hi * Wi;
    float g0 = lp[y0 * Wi + x0] * (1.f - wy) + lp[y1 * Wi + x0] * wy;
    float g1 = lp[y0 * Wi + x1] * (1.f - wy) + lp[y1 * Wi + x1] * wy;
    out[idx] = skip[idx] + g0 * (1.f - wx) + g1 * wx;
}

// --------------------------- BN + GELU elementwise -------------------------
__global__ void k_bn_gelu(const float* __restrict__ x, const float* __restrict__ s,
                          const float* __restrict__ b, float* __restrict__ out, int L) {
    int idx = blockIdx.x * 256 + threadIdx.x;            // (b,c,l)
    int total = B_ * C_ * L;
    if (idx >= total) return;
    int t = idx / L; int c = t % C_;
    out[idx] = geluf(x[idx] * (s[c] * BNS_) + b[c]);
}

// --------------------------- diagnostic fill (f32) -------------------------
__global__ void k_fill_out(float* o, int n, float v) {
    int i = blockIdx.x * 256 + threadIdx.x;
    if (i < n) o[i] = v;
}

// ===========================================================================
struct VssW {
    const float *lnw, *lnb, *inproj, *convw, *convb, *xproj, *dtw, *dtb, *Alog, *D, *onw, *onb, *outproj;
};

static void run_vss(const float* xc_in, float* xc_out, const VssW& p, int H, int W,
                    float* xln, float* xz, float* xm, float* xdbl,
                    float* ybuf, float* tbuf, hipStream_t stream) {
    int L = H * W, M = B_ * L;
    n_ln_nchw<<<(M + 255) / 256, 256, 0, stream>>>(xc_in, p.lnw, p.lnb, xln, L, M, 1e-6f);
    {
        int tot = M * 2 * DI_;
        n_gemm_nt<0><<<(tot + 255) / 256, 256, 0, stream>>>(xln, p.inproj, xz, M, 2 * DI_, C_, nullptr, L);
    }
    {
        int tot = B_ * L * DI_;
        n_dwconv_silu<<<(tot + 255) / 256, 256, 0, stream>>>(xz, p.convw, p.convb, xm, H, W);
    }
    {
        int tot = B_ * K_ * 64 * L;
        n_xdbl<<<(tot + 255) / 256, 256, 0, stream>>>(xm, p.xproj, xdbl, H, W);
    }
    for (int kd = 0; kd < K_; kd++) {
        k_scan_dir<<<B_ * DI_ / 256, 256, 0, stream>>>(
            xm, xdbl, p.dtw, p.dtb, p.Alog, p.D, ybuf, H, W, kd, kd ? 1 : 0);
    }
    n_ln_silu<<<(M + 255) / 256, 256, 0, stream>>>(ybuf, xz, p.onw, p.onb, tbuf, M);
    {
        int tot = M * C_;
        n_gemm_nt<1><<<(tot + 255) / 256, 256, 0, stream>>>(tbuf, p.outproj, xc_out, M, C_, DI_, xc_in, L);
    }
}

extern "C" void kernel_launch(void* const* d_in, const int* in_sizes, int n_in,
                              void* d_out, int out_size, void* d_ws, size_t ws_size,
                              hipStream_t stream) {
    // ---- diagnostic 1: input ordering/sizes ----
    bool sizes_ok = (n_in == 31)
        && in_sizes[0]  == 524288      // x
        && in_sizes[3]  == 5242880     // vss_in_proj
        && in_sizes[6]  == 1310720     // vss_xproj
        && in_sizes[7]  == 655360      // vss_dtw
        && in_sizes[9]  == 327680      // vss_Alog
        && in_sizes[13] == 2621440     // vss_outproj
        && in_sizes[17] == 524288      // ds_pw
        && in_sizes[20] == 4718592     // fus_c1
        && in_sizes[28] == 2359296;    // op_conv
    if (!sizes_ok) {
        k_fill_out<<<(out_size + 255) / 256, 256, 0, stream>>>((float*)d_out, out_size, 100.0f);
        return;
    }

    constexpr size_t NEED_FLOATS = 10584064;
    constexpr size_t NEED_BYTES  = NEED_FLOATS * 4;   // 42,336,256
    if (ws_size < NEED_BYTES) {
        k_fill_out<<<(out_size + 255) / 256, 256, 0, stream>>>((float*)d_out, out_size, 0.0f);
        return;
    }

    const float* x        = (const float*)d_in[0];
    const float* lnw      = (const float*)d_in[1];
    const float* lnb      = (const float*)d_in[2];
    const float* inproj   = (const float*)d_in[3];
    const float* convw    = (const float*)d_in[4];
    const float* convb    = (const float*)d_in[5];
    const float* xprojp   = (const float*)d_in[6];
    const float* dtwp     = (const float*)d_in[7];
    const float* dtbp     = (const float*)d_in[8];
    const float* Alogp    = (const float*)d_in[9];
    const float* Dpp      = (const float*)d_in[10];
    const float* onwp     = (const float*)d_in[11];
    const float* onbp     = (const float*)d_in[12];
    const float* outprojp = (const float*)d_in[13];
    const float* ds_dw    = (const float*)d_in[14];
    const float* ds_bn1s  = (const float*)d_in[15];
    const float* ds_bn1b  = (const float*)d_in[16];
    const float* ds_pw    = (const float*)d_in[17];
    const float* ds_bn2s  = (const float*)d_in[18];
    const float* ds_bn2b  = (const float*)d_in[19];
    const float* fus_c1   = (const float*)d_in[20];
    const float* fus_bn1s = (const float*)d_in[21];
    const float* fus_bn1b = (const float*)d_in[22];
    const float* fus_c2   = (const float*)d_in[23];
    const float* fus_bn2s = (const float*)d_in[24];
    const float* fus_bn2b = (const float*)d_in[25];
    const float* op_bn0s  = (const float*)d_in[26];
    const float* op_bn0b  = (const float*)d_in[27];
    const float* op_conv  = (const float*)d_in[28];
    const float* op_bn1s  = (const float*)d_in[29];
    const float* op_bn1b  = (const float*)d_in[30];

    float* ws = (float*)d_ws;
    size_t off = 0;
    float* xln   = ws + off; off += 524288;
    float* xz    = ws + off; off += 2097152;
    float* xm    = ws + off; off += 1048576;
    float* xdbl  = ws + off; off += 262144;
    float* ybuf  = ws + off; off += 1048576;
    float* tbuf  = ws + off; off += 1048576;
    float* t_a   = ws + off; off += 524288;
    float* xr    = ws + off; off += 524288;
    float* p1    = ws + off; off += 131072;
    float* p2    = ws + off; off += 32768;
    float* proc0 = ws + off; off += 524288;
    float* proc1 = ws + off; off += 131072;
    float* proc2 = ws + off; off += 32768;
    float* p1pre = ws + off; off += 131072;
    float* p2pre = ws + off; off += 32768;
    float* up1t  = ws + off; off += 131072;
    float* rbh1  = ws + off; off += 131072;
    float* fus1  = ws + off; off += 131072;
    float* up0t  = ws + off; off += 524288;
    float* rbh0  = ws + off; off += 524288;
    float* fus0  = ws + off; off += 524288;
    float* hbuf  = ws + off; off += 524288;

    VssW vp[5];
    for (int i = 0; i < 5; i++) {
        vp[i].lnw     = lnw + (size_t)i * C_;
        vp[i].lnb     = lnb + (size_t)i * C_;
        vp[i].inproj  = inproj + (size_t)i * 2 * DI_ * C_;
        vp[i].convw   = convw + (size_t)i * DI_ * 9;
        vp[i].convb   = convb + (size_t)i * DI_;
        vp[i].xproj   = xprojp + (size_t)i * K_ * 64 * DI_;
        vp[i].dtw     = dtwp + (size_t)i * K_ * DI_ * R_;
        vp[i].dtb     = dtbp + (size_t)i * K_ * DI_;
        vp[i].Alog    = Alogp + (size_t)i * K_ * DI_ * N_;
        vp[i].D       = Dpp + (size_t)i * K_ * DI_;
        vp[i].onw     = onwp + (size_t)i * DI_;
        vp[i].onb     = onbp + (size_t)i * DI_;
        vp[i].outproj = outprojp + (size_t)i * C_ * DI_;
    }

    // ---- stem: two VSS at 16x16 ----
    run_vss(x,   t_a, vp[0], 16, 16, xln, xz, xm, xdbl, ybuf, tbuf, stream);
    run_vss(t_a, xr,  vp[1], 16, 16, xln, xz, xm, xdbl, ybuf, tbuf, stream);

    // ---- down 0: 16 -> 8 ----
    k_dwconv_s2_bn_gelu<<<(B_ * C_ * 64 + 255) / 256, 256, 0, stream>>>(
        xr, ds_dw, ds_bn1s, ds_bn1b, p1pre, 16, 16);
    k_pwconv_bn_gelu<<<(B_ * C_ * 64 + 255) / 256, 256, 0, stream>>>(
        p1pre, ds_pw, ds_bn2s, ds_bn2b, p1, 64);
    // ---- down 1: 8 -> 4 ----
    k_dwconv_s2_bn_gelu<<<(B_ * C_ * 16 + 255) / 256, 256, 0, stream>>>(
        p1, ds_dw + (size_t)C_ * 9, ds_bn1s + C_, ds_bn1b + C_, p2pre, 8, 8);
    k_pwconv_bn_gelu<<<(B_ * C_ * 16 + 255) / 256, 256, 0, stream>>>(
        p2pre, ds_pw + (size_t)C_ * C_, ds_bn2s + C_, ds_bn2b + C_, p2, 16);

    // ---- per-scale VSS ----
    run_vss(xr, proc0, vp[2], 16, 16, xln, xz, xm, xdbl, ybuf, tbuf, stream);
    run_vss(p1, proc1, vp[3],  8,  8, xln, xz, xm, xdbl, ybuf, tbuf, stream);
    run_vss(p2, proc2, vp[4],  4,  4, xln, xz, xm, xdbl, ybuf, tbuf, stream);

    // ---- fuse i=1: up(proc2: 4->8) + proc1, resblk j=0 ----
    k_up_add<<<(B_ * C_ * 64 + 255) / 256, 256, 0, stream>>>(proc2, proc1, up1t, 4, 4, 8, 8);
    {
        int tot = B_ * C_ * 64;
        n_conv3x3<0><<<(tot + 255) / 256, 256, 0, stream>>>(up1t, fus_c1, fus_bn1s, fus_bn1b,
                                                            nullptr, rbh1, 8, 8);
        n_conv3x3<1><<<(tot + 255) / 256, 256, 0, stream>>>(rbh1, fus_c2, fus_bn2s, fus_bn2b,
                                                            up1t, fus1, 8, 8);
    }
    // ---- fuse i=0: up(fus1: 8->16) + proc0, resblk j=1 ----
    k_up_add<<<(B_ * C_ * 256 + 255) / 256, 256, 0, stream>>>(fus1, proc0, up0t, 8, 8, 16, 16);
    {
        int tot = B_ * C_ * 256;
        n_conv3x3<0><<<(tot + 255) / 256, 256, 0, stream>>>(up0t, fus_c1 + (size_t)C_ * C_ * 9,
                                                            fus_bn1s + C_, fus_bn1b + C_,
                                                            nullptr, rbh0, 16, 16);
        n_conv3x3<1><<<(tot + 255) / 256, 256, 0, stream>>>(rbh0, fus_c2 + (size_t)C_ * C_ * 9,
                                                            fus_bn2s + C_, fus_bn2b + C_,
                                                            up0t, fus0, 16, 16);
    }

    // ---- output head ----
    k_bn_gelu<<<(B_ * C_ * 256 + 255) / 256, 256, 0, stream>>>(fus0, op_bn0s, op_bn0b, hbuf, 256);
    {
        int tot = B_ * C_ * 256;
        n_conv3x3<2><<<(tot + 255) / 256, 256, 0, stream>>>(hbuf, op_conv, op_bn1s, op_bn1b,
                                                            x, (float*)d_out, 16, 16);
    }
    (void)out_size;
}

// Round 5
// 10805.712 us; speedup vs baseline: 4.9264x; 4.9264x over previous
//
#include <hip/hip_runtime.h>
#include <hip/hip_bf16.h>
#include <math.h>

// ---------------------------------------------------------------------------
// HMABottleneck: B=4, C=512, H=W=16, DI=1024, K=4 dirs, N=16 states, R=32
// Round 5: perf round. Fixes from profile:
//  - scan: register arrays (unroll), single dispatch for all 4 dirs + merge
//  - GEMM: validated 64x64 LDS-tiled kernel (round-0)
//  - LN/xdbl: validated LDS versions (round-0)
//  - conv3x3: LDS plane staging, 8 output channels per block
// ---------------------------------------------------------------------------

constexpr int B_  = 4;
constexpr int C_  = 512;
constexpr int DI_ = 1024;
constexpr int K_  = 4;
constexpr int N_  = 16;
constexpr int R_  = 32;
constexpr float BNS_ = 0.9999950000374997f;   // 1/sqrt(1+1e-5)

__device__ inline float geluf(float x) {
    return 0.5f * x * (1.0f + erff(x * 0.70710678118654752f));
}
__device__ inline float siluf(float x) {
    return x / (1.0f + expf(-x));
}
__device__ inline float softplusf(float x) {
    return fmaxf(x, 0.0f) + log1pf(expf(-fabsf(x)));
}

__device__ inline float blockReduceSum(float v, float* sd) {
    int tid = threadIdx.x;
    sd[tid] = v; __syncthreads();
    for (int s = blockDim.x / 2; s > 0; s >>= 1) {
        if (tid < s) sd[tid] += sd[tid + s];
        __syncthreads();
    }
    float r = sd[0]; __syncthreads();
    return r;
}

// --------------------------- LN over channels (NCHW -> (B*L, C)) -----------
__global__ void k_ln_nchw(const float* __restrict__ x, const float* __restrict__ w,
                          const float* __restrict__ b, float* __restrict__ out,
                          int L, float eps) {
    int row = blockIdx.x;            // b*L + l
    int bb = row / L, l = row % L;
    __shared__ float sd[256];
    __shared__ float srow[C_];
    const float* xp = x + (size_t)bb * C_ * L + l;
    float sum = 0.f;
    for (int c = threadIdx.x; c < C_; c += 256) { float v = xp[(size_t)c * L]; srow[c] = v; sum += v; }
    sum = blockReduceSum(sum, sd);
    float mu = sum / C_;
    float vs = 0.f;
    for (int c = threadIdx.x; c < C_; c += 256) { float d = srow[c] - mu; vs += d * d; }
    vs = blockReduceSum(vs, sd);
    float rstd = rsqrtf(vs / C_ + eps);
    float* op = out + (size_t)row * C_;
    for (int c = threadIdx.x; c < C_; c += 256) op[c] = (srow[c] - mu) * rstd * w[c] + b[c];
}

// --------------------------- tiled f32 GEMM: out = A (M,K) * Bw(N,K)^T -----
// EPI 0: Cout[m*Nn+n] = acc
// EPI 1: m=(b,l): Cout[(b*C_+n)*L + l] = Res[same] + acc   (NCHW residual)
template <int EPI>
__global__ void k_gemm_nt(const float* __restrict__ A, const float* __restrict__ Bw,
                          float* __restrict__ Cout, int M, int Nn, int Kk,
                          const float* __restrict__ Res, int L) {
    const int BK = 16;
    __shared__ float As[BK][65];
    __shared__ float Bs[BK][65];
    int m0 = blockIdx.y * 64, n0 = blockIdx.x * 64;
    int tid = threadIdx.x;
    int tx = tid % 16, ty = tid / 16;
    float acc[4][4] = {};
    for (int k0 = 0; k0 < Kk; k0 += BK) {
        int mm = tid >> 2;
        int kk = (tid & 3) * 4;
        float4 va = *reinterpret_cast<const float4*>(A + (size_t)(m0 + mm) * Kk + k0 + kk);
        As[kk + 0][mm] = va.x; As[kk + 1][mm] = va.y; As[kk + 2][mm] = va.z; As[kk + 3][mm] = va.w;
        float4 vb = *reinterpret_cast<const float4*>(Bw + (size_t)(n0 + mm) * Kk + k0 + kk);
        Bs[kk + 0][mm] = vb.x; Bs[kk + 1][mm] = vb.y; Bs[kk + 2][mm] = vb.z; Bs[kk + 3][mm] = vb.w;
        __syncthreads();
#pragma unroll
        for (int k = 0; k < BK; ++k) {
            float a[4], b2[4];
#pragma unroll
            for (int i = 0; i < 4; i++) a[i] = As[k][ty + 16 * i];
#pragma unroll
            for (int j = 0; j < 4; j++) b2[j] = Bs[k][tx + 16 * j];
#pragma unroll
            for (int i = 0; i < 4; i++)
#pragma unroll
                for (int j = 0; j < 4; j++) acc[i][j] += a[i] * b2[j];
        }
        __syncthreads();
    }
#pragma unroll
    for (int i = 0; i < 4; i++) {
        int m = m0 + ty + 16 * i;
#pragma unroll
        for (int j = 0; j < 4; j++) {
            int n = n0 + tx + 16 * j;
            if (EPI == 0) {
                Cout[(size_t)m * Nn + n] = acc[i][j];
            } else {
                int bb = m / L, l = m % L;
                size_t o = ((size_t)bb * C_ + n) * L + l;
                Cout[o] = Res[o] + acc[i][j];
            }
        }
    }
}

// --------------------------- depthwise 3x3 (pad1) + bias + SiLU ------------
__global__ void k_dwconv_silu(const float* __restrict__ xz, const float* __restrict__ cw,
                              const float* __restrict__ cb, float* __restrict__ xm,
                              int H, int W) {
    int L = H * W;
    int idx = blockIdx.x * 256 + threadIdx.x;            // (b, l, d) d fastest
    int total = B_ * L * DI_;
    if (idx >= total) return;
    int d = idx % DI_; int t = idx / DI_; int l = t % L; int bb = t / L;
    int h = l / W, w = l % W;
    float acc = cb[d];
    const float* wp = cw + d * 9;
#pragma unroll
    for (int dy = 0; dy < 3; dy++) {
        int hh = h + dy - 1;
        if ((unsigned)hh >= (unsigned)H) continue;
#pragma unroll
        for (int dx = 0; dx < 3; dx++) {
            int ww = w + dx - 1;
            if ((unsigned)ww >= (unsigned)W) continue;
            acc += xz[((size_t)bb * L + hh * W + ww) * (2 * DI_) + d] * wp[dy * 3 + dx];
        }
    }
    xm[idx] = siluf(acc);
}

// map (k,l) -> source flat index in row-major (h*W+w) order
__device__ inline int dir_src(int k, int l, int H, int W, int L) {
    int ll = (k >= 2) ? (L - 1 - l) : l;
    return (k & 1) ? ((ll % H) * W + ll / H) : ll;
}

// --------------------------- x_dbl (LDS row staging, 64 thr/block) ---------
__global__ void k_xdbl(const float* __restrict__ xm, const float* __restrict__ xproj,
                       float* __restrict__ xdbl, int H, int W) {
    int L = H * W;
    int blk = blockIdx.x;            // (b,k,l)
    int l = blk % L; int t = blk / L; int k = t % K_; int bb = t / K_;
    int src = dir_src(k, l, H, W, L);
    __shared__ float row[DI_];
    const float* xp = xm + ((size_t)bb * L + src) * DI_;
    for (int d = threadIdx.x; d < DI_; d += 64) row[d] = xp[d];
    __syncthreads();
    const float* wp = xproj + ((size_t)k * 64 + threadIdx.x) * DI_;
    float acc = 0.f;
    for (int d = 0; d < DI_; d++) acc += row[d] * wp[d];
    xdbl[((size_t)(bb * K_ + k) * 64 + threadIdx.x) * L + l] = acc;
}

// --------------------------- fused delta + scan, all 4 dirs ----------------
// One thread per (b,k,d); 64-thread blocks. Writes per-direction partials:
// part[((b*K+k)*L + src(k,l))*DI + d] = step-l output.
__global__ void k_scan_all(const float* __restrict__ xm, const float* __restrict__ xdbl,
                           const float* __restrict__ dtw, const float* __restrict__ dtb,
                           const float* __restrict__ Alog, const float* __restrict__ Dp,
                           float* __restrict__ part, int H, int W) {
    int L = H * W;
    int idx = blockIdx.x * 64 + threadIdx.x;     // (b,k,d) d fastest
    int d = idx % DI_; int t = idx / DI_; int k = t % K_; int bb = t / K_;
    float wreg[R_];
    const float* wp = dtw + ((size_t)k * DI_ + d) * R_;
#pragma unroll
    for (int r = 0; r < R_; r++) wreg[r] = wp[r];
    float A[N_], h[N_];
    const float* al = Alog + ((size_t)k * DI_ + d) * N_;
#pragma unroll
    for (int n = 0; n < N_; n++) { A[n] = -expf(al[n]); h[n] = 0.f; }
    float Dv = Dp[k * DI_ + d];
    float bias = dtb[k * DI_ + d];
    const float* bc = xdbl + (size_t)(bb * K_ + k) * 64 * L;
    const float* xmb = xm + (size_t)bb * L * DI_ + d;
    float* yb = part + (size_t)(bb * K_ + k) * L * DI_ + d;
    for (int l = 0; l < L; l++) {
        int src = dir_src(k, l, H, W, L);
        float u = xmb[(size_t)src * DI_];
        float acc = bias;
#pragma unroll
        for (int r = 0; r < R_; r++) acc += bc[(size_t)r * L + l] * wreg[r];
        float dl = softplusf(acc);
        float du = dl * u;
        float y = 0.f;
#pragma unroll
        for (int n = 0; n < N_; n++) {
            float Bl = bc[(size_t)(R_ + n) * L + l];
            float Cl = bc[(size_t)(R_ + N_ + n) * L + l];
            h[n] = expf(dl * A[n]) * h[n] + du * Bl;
            y += h[n] * Cl;
        }
        yb[(size_t)src * DI_] = y + Dv * u;
    }
}

// --------------------------- merge 4 direction partials --------------------
__global__ void k_merge4(const float* __restrict__ part, float* __restrict__ ybuf,
                         int L) {
    int idx = blockIdx.x * 256 + threadIdx.x;    // (b,l,d)
    int total = B_ * L * DI_;
    if (idx >= total) return;
    int d = idx % DI_; int t = idx / DI_; int l = t % L; int bb = t / L;
    size_t s = ((size_t)bb * K_ * L + l) * DI_ + d;
    float v = part[s] + part[s + (size_t)L * DI_] + part[s + (size_t)2 * L * DI_]
            + part[s + (size_t)3 * L * DI_];
    ybuf[idx] = v;
}

// --------------------------- LN(y) * silu(z) -> t (B*L, DI) ----------------
__global__ void k_ln_silu(const float* __restrict__ y, const float* __restrict__ xz,
                          const float* __restrict__ onw, const float* __restrict__ onb,
                          float* __restrict__ tout) {
    int row = blockIdx.x;            // b*L + l
    __shared__ float sd[256];
    __shared__ float srow[DI_];
    const float* yp = y + (size_t)row * DI_;
    float sum = 0.f;
    for (int d = threadIdx.x; d < DI_; d += 256) { float v = yp[d]; srow[d] = v; sum += v; }
    sum = blockReduceSum(sum, sd);
    float mu = sum / DI_;
    float vs = 0.f;
    for (int d = threadIdx.x; d < DI_; d += 256) { float dv = srow[d] - mu; vs += dv * dv; }
    vs = blockReduceSum(vs, sd);
    float rstd = rsqrtf(vs / DI_ + 1e-5f);
    const float* zp = xz + (size_t)row * 2 * DI_ + DI_;
    float* tp = tout + (size_t)row * DI_;
    for (int d = threadIdx.x; d < DI_; d += 256) {
        float zn = zp[d];
        tp[d] = ((srow[d] - mu) * rstd * onw[d] + onb[d]) * siluf(zn);
    }
}

// --------------------------- downsample: dw conv s2 + BN + GELU ------------
__global__ void k_dwconv_s2_bn_gelu(const float* __restrict__ x, const float* __restrict__ dw,
                                    const float* __restrict__ bns, const float* __restrict__ bnb,
                                    float* __restrict__ out, int Hi, int Wi) {
    int Ho = Hi / 2, Wo = Wi / 2;
    int idx = blockIdx.x * 256 + threadIdx.x;            // (b,c,ho,wo)
    int total = B_ * C_ * Ho * Wo;
    if (idx >= total) return;
    int wo = idx % Wo; int t = idx / Wo; int ho = t % Ho; t /= Ho; int c = t % C_; int bb = t / C_;
    float acc = 0.f;
    const float* xp = x + ((size_t)bb * C_ + c) * Hi * Wi;
    const float* wp = dw + c * 9;
#pragma unroll
    for (int dy = 0; dy < 3; dy++) {
        int ih = ho * 2 + dy - 1;
        if ((unsigned)ih >= (unsigned)Hi) continue;
#pragma unroll
        for (int dx = 0; dx < 3; dx++) {
            int iw = wo * 2 + dx - 1;
            if ((unsigned)iw >= (unsigned)Wi) continue;
            acc += xp[ih * Wi + iw] * wp[dy * 3 + dx];
        }
    }
    acc = acc * (bns[c] * BNS_) + bnb[c];
    out[idx] = geluf(acc);
}

// --------------------------- pointwise 1x1 conv + BN + GELU ----------------
__global__ void k_pwconv_bn_gelu(const float* __restrict__ x, const float* __restrict__ pw,
                                 const float* __restrict__ bns, const float* __restrict__ bnb,
                                 float* __restrict__ out, int L) {
    int idx = blockIdx.x * 256 + threadIdx.x;            // (b,co,l)
    int total = B_ * C_ * L;
    if (idx >= total) return;
    int l = idx % L; int t = idx / L; int co = t % C_; int bb = t / C_;
    const float* xp = x + (size_t)bb * C_ * L + l;
    const float* wp = pw + (size_t)co * C_;
    float acc = 0.f;
    for (int ci = 0; ci < C_; ci++) acc += xp[(size_t)ci * L] * wp[ci];
    acc = acc * (bns[co] * BNS_) + bnb[co];
    out[idx] = geluf(acc);
}

// --------------------------- 3x3 conv, LDS plane staging -------------------
// block = L threads (one per (h,w)), 8 output channels per block.
// grid.x = B_ * (C_/8)
// MODE 0: out = gelu(bn(conv));  MODE 1: out = gelu(bn(conv)+res)
// MODE 2: out = gelu(bn(conv)) + res   (final head output, f32)
template <int MODE>
__global__ void k_conv3x3_lds(const float* __restrict__ x, const float* __restrict__ wgt,
                              const float* __restrict__ bns, const float* __restrict__ bnb,
                              const float* __restrict__ res, float* __restrict__ out,
                              int H, int W) {
    const int COB = 8;
    int L = H * W;
    int t = threadIdx.x;
    int h = t / W, w = t % W;
    int blk = blockIdx.x;
    int ng = C_ / COB;
    int cg = blk % ng; int bb = blk / ng;
    int co0 = cg * COB;
    __shared__ float plane[2][257];
    float acc[COB];
#pragma unroll
    for (int j = 0; j < COB; j++) acc[j] = 0.f;
    const float* xb = x + (size_t)bb * C_ * L;
    int p = 0;
    for (int ci = 0; ci < C_; ci++) {
        plane[p][t] = xb[(size_t)ci * L + t];
        __syncthreads();
        float v[9];
#pragma unroll
        for (int dy = 0; dy < 3; dy++) {
            int hh = h + dy - 1;
            bool hok = (unsigned)hh < (unsigned)H;
#pragma unroll
            for (int dx = 0; dx < 3; dx++) {
                int ww = w + dx - 1;
                bool ok = hok && ((unsigned)ww < (unsigned)W);
                v[dy * 3 + dx] = ok ? plane[p][hh * W + ww] : 0.f;
            }
        }
        const float* wr = wgt + ((size_t)co0 * C_ + ci) * 9;
#pragma unroll
        for (int j = 0; j < COB; j++) {
            const float* wj = wr + (size_t)j * C_ * 9;
            float a = acc[j];
#pragma unroll
            for (int q = 0; q < 9; q++) a += v[q] * wj[q];
            acc[j] = a;
        }
        p ^= 1;
    }
#pragma unroll
    for (int j = 0; j < COB; j++) {
        int co = co0 + j;
        float a = acc[j] * (bns[co] * BNS_) + bnb[co];
        size_t o = (((size_t)bb * C_ + co) * H + h) * W + w;
        if (MODE == 0) out[o] = geluf(a);
        else if (MODE == 1) out[o] = geluf(a + res[o]);
        else out[o] = geluf(a) + res[o];
    }
}

// --------------------------- bilinear up + skip add ------------------------
__global__ void k_up_add(const float* __restrict__ low, const float* __restrict__ skip,
                         float* __restrict__ out, int Hi, int Wi, int Ho, int Wo) {
    int idx = blockIdx.x * 256 + threadIdx.x;            // (b,c,ho,wo)
    int total = B_ * C_ * Ho * Wo;
    if (idx >= total) return;
    int wo = idx % Wo; int t = idx / Wo; int ho = t % Ho; t /= Ho; int c = t % C_; int bb = t / C_;
    float fy = (float)ho * (float)(Hi - 1) / (float)(Ho - 1);
    float fx = (float)wo * (float)(Wi - 1) / (float)(Wo - 1);
    int y0 = (int)floorf(fy); int y1 = min(y0 + 1, Hi - 1); float wy = fy - (float)y0;
    int x0 = (int)floorf(fx); int x1 = min(x0 + 1, Wi - 1); float wx = fx - (float)x0;
    const float* lp = low + ((size_t)bb * C_ + c) * Hi * Wi;
    float g0 = lp[y0 * Wi + x0] * (1.f - wy) + lp[y1 * Wi + x0] * wy;
    float g1 = lp[y0 * Wi + x1] * (1.f - wy) + lp[y1 * Wi + x1] * wy;
    out[idx] = skip[idx] + g0 * (1.f - wx) + g1 * wx;
}

// --------------------------- BN + GELU elementwise -------------------------
__global__ void k_bn_gelu(const float* __restrict__ x, const float* __restrict__ s,
                          const float* __restrict__ b, float* __restrict__ out, int L) {
    int idx = blockIdx.x * 256 + threadIdx.x;            // (b,c,l)
    int total = B_ * C_ * L;
    if (idx >= total) return;
    int t = idx / L; int c = t % C_;
    out[idx] = geluf(x[idx] * (s[c] * BNS_) + b[c]);
}

// --------------------------- diagnostic fill (f32) -------------------------
__global__ void k_fill_out(float* o, int n, float v) {
    int i = blockIdx.x * 256 + threadIdx.x;
    if (i < n) o[i] = v;
}

// ===========================================================================
struct VssW {
    const float *lnw, *lnb, *inproj, *convw, *convb, *xproj, *dtw, *dtb, *Alog, *D, *onw, *onb, *outproj;
};

static void run_vss(const float* xc_in, float* xc_out, const VssW& p, int H, int W,
                    float* xln, float* xz, float* xm, float* xdbl,
                    float* part, float* ybuf, float* tbuf, hipStream_t stream) {
    int L = H * W, M = B_ * L;
    k_ln_nchw<<<M, 256, 0, stream>>>(xc_in, p.lnw, p.lnb, xln, L, 1e-6f);
    {
        dim3 g(2 * DI_ / 64, M / 64);
        k_gemm_nt<0><<<g, 256, 0, stream>>>(xln, p.inproj, xz, M, 2 * DI_, C_, nullptr, L);
    }
    {
        int tot = B_ * L * DI_;
        k_dwconv_silu<<<(tot + 255) / 256, 256, 0, stream>>>(xz, p.convw, p.convb, xm, H, W);
    }
    k_xdbl<<<B_ * K_ * L, 64, 0, stream>>>(xm, p.xproj, xdbl, H, W);
    k_scan_all<<<B_ * K_ * DI_ / 64, 64, 0, stream>>>(
        xm, xdbl, p.dtw, p.dtb, p.Alog, p.D, part, H, W);
    {
        int tot = B_ * L * DI_;
        k_merge4<<<(tot + 255) / 256, 256, 0, stream>>>(part, ybuf, L);
    }
    k_ln_silu<<<M, 256, 0, stream>>>(ybuf, xz, p.onw, p.onb, tbuf);
    {
        dim3 g(C_ / 64, M / 64);
        k_gemm_nt<1><<<g, 256, 0, stream>>>(tbuf, p.outproj, xc_out, M, C_, DI_, xc_in, L);
    }
}

extern "C" void kernel_launch(void* const* d_in, const int* in_sizes, int n_in,
                              void* d_out, int out_size, void* d_ws, size_t ws_size,
                              hipStream_t stream) {
    constexpr size_t NEED_FLOATS = 11075584;
    constexpr size_t NEED_BYTES  = NEED_FLOATS * 4;   // 44,302,336
    if (ws_size < NEED_BYTES) {
        k_fill_out<<<(out_size + 255) / 256, 256, 0, stream>>>((float*)d_out, out_size, 0.0f);
        return;
    }

    const float* x        = (const float*)d_in[0];
    const float* lnw      = (const float*)d_in[1];
    const float* lnb      = (const float*)d_in[2];
    const float* inproj   = (const float*)d_in[3];
    const float* convw    = (const float*)d_in[4];
    const float* convb    = (const float*)d_in[5];
    const float* xprojp   = (const float*)d_in[6];
    const float* dtwp     = (const float*)d_in[7];
    const float* dtbp     = (const float*)d_in[8];
    const float* Alogp    = (const float*)d_in[9];
    const float* Dpp      = (const float*)d_in[10];
    const float* onwp     = (const float*)d_in[11];
    const float* onbp     = (const float*)d_in[12];
    const float* outprojp = (const float*)d_in[13];
    const float* ds_dw    = (const float*)d_in[14];
    const float* ds_bn1s  = (const float*)d_in[15];
    const float* ds_bn1b  = (const float*)d_in[16];
    const float* ds_pw    = (const float*)d_in[17];
    const float* ds_bn2s  = (const float*)d_in[18];
    const float* ds_bn2b  = (const float*)d_in[19];
    const float* fus_c1   = (const float*)d_in[20];
    const float* fus_bn1s = (const float*)d_in[21];
    const float* fus_bn1b = (const float*)d_in[22];
    const float* fus_c2   = (const float*)d_in[23];
    const float* fus_bn2s = (const float*)d_in[24];
    const float* fus_bn2b = (const float*)d_in[25];
    const float* op_bn0s  = (const float*)d_in[26];
    const float* op_bn0b  = (const float*)d_in[27];
    const float* op_conv  = (const float*)d_in[28];
    const float* op_bn1s  = (const float*)d_in[29];
    const float* op_bn1b  = (const float*)d_in[30];

    float* ws = (float*)d_ws;
    // layout (floats)
    float* xln   = ws;                    // 524288
    float* xz    = ws + 524288;           // 2097152
    float* xm    = ws + 2621440;          // 1048576
    float* xdbl  = ws + 3670016;          // 262144
    float* ybuf  = ws + 3932160;          // 1048576
    float* part  = ws + 4980736;          // 4194304
    float* tbuf  = part;                  // alias: part dead before ln_silu
    float* t_a   = ws + 9175040;          // 524288
    float* xr    = ws + 9699328;          // 524288
    float* p1    = ws + 10223616;         // 131072
    float* p2    = ws + 10354688;         // 32768
    float* proc0 = ws + 10387456;         // 524288
    float* proc1 = ws + 10911744;         // 131072
    float* proc2 = ws + 11042816;         // 32768
    // down-path temps (alias xz; consumed before next VSS rewrites xz)
    float* p1pre = xz;                    // 131072
    float* p2pre = xz + 131072;           // 32768
    // fusion temps (all VSS dead by then)
    float* up1t  = xln;                   // 131072
    float* rbh1  = xln + 131072;          // 131072
    float* fus1  = xln + 262144;          // 131072
    float* up0t  = xm;                    // 524288
    float* rbh0  = part;                  // 524288
    float* fus0  = part + 524288;         // 524288
    float* hbuf  = part + 1048576;        // 524288

    VssW vp[5];
    for (int i = 0; i < 5; i++) {
        vp[i].lnw     = lnw + (size_t)i * C_;
        vp[i].lnb     = lnb + (size_t)i * C_;
        vp[i].inproj  = inproj + (size_t)i * 2 * DI_ * C_;
        vp[i].convw   = convw + (size_t)i * DI_ * 9;
        vp[i].convb   = convb + (size_t)i * DI_;
        vp[i].xproj   = xprojp + (size_t)i * K_ * 64 * DI_;
        vp[i].dtw     = dtwp + (size_t)i * K_ * DI_ * R_;
        vp[i].dtb     = dtbp + (size_t)i * K_ * DI_;
        vp[i].Alog    = Alogp + (size_t)i * K_ * DI_ * N_;
        vp[i].D       = Dpp + (size_t)i * K_ * DI_;
        vp[i].onw     = onwp + (size_t)i * DI_;
        vp[i].onb     = onbp + (size_t)i * DI_;
        vp[i].outproj = outprojp + (size_t)i * C_ * DI_;
    }

    // ---- stem: two VSS at 16x16 ----
    run_vss(x,   t_a, vp[0], 16, 16, xln, xz, xm, xdbl, part, ybuf, tbuf, stream);
    run_vss(t_a, xr,  vp[1], 16, 16, xln, xz, xm, xdbl, part, ybuf, tbuf, stream);

    // ---- down 0: 16 -> 8 ----
    k_dwconv_s2_bn_gelu<<<(B_ * C_ * 64 + 255) / 256, 256, 0, stream>>>(
        xr, ds_dw, ds_bn1s, ds_bn1b, p1pre, 16, 16);
    k_pwconv_bn_gelu<<<(B_ * C_ * 64 + 255) / 256, 256, 0, stream>>>(
        p1pre, ds_pw, ds_bn2s, ds_bn2b, p1, 64);
    // ---- down 1: 8 -> 4 ----
    k_dwconv_s2_bn_gelu<<<(B_ * C_ * 16 + 255) / 256, 256, 0, stream>>>(
        p1, ds_dw + (size_t)C_ * 9, ds_bn1s + C_, ds_bn1b + C_, p2pre, 8, 8);
    k_pwconv_bn_gelu<<<(B_ * C_ * 16 + 255) / 256, 256, 0, stream>>>(
        p2pre, ds_pw + (size_t)C_ * C_, ds_bn2s + C_, ds_bn2b + C_, p2, 16);

    // ---- per-scale VSS ----
    run_vss(xr, proc0, vp[2], 16, 16, xln, xz, xm, xdbl, part, ybuf, tbuf, stream);
    run_vss(p1, proc1, vp[3],  8,  8, xln, xz, xm, xdbl, part, ybuf, tbuf, stream);
    run_vss(p2, proc2, vp[4],  4,  4, xln, xz, xm, xdbl, part, ybuf, tbuf, stream);

    // ---- fuse i=1: up(proc2: 4->8) + proc1, resblk j=0 ----
    k_up_add<<<(B_ * C_ * 64 + 255) / 256, 256, 0, stream>>>(proc2, proc1, up1t, 4, 4, 8, 8);
    {
        dim3 g(B_ * (C_ / 8));
        k_conv3x3_lds<0><<<g, 64, 0, stream>>>(up1t, fus_c1, fus_bn1s, fus_bn1b,
                                               nullptr, rbh1, 8, 8);
        k_conv3x3_lds<1><<<g, 64, 0, stream>>>(rbh1, fus_c2, fus_bn2s, fus_bn2b,
                                               up1t, fus1, 8, 8);
    }
    // ---- fuse i=0: up(fus1: 8->16) + proc0, resblk j=1 ----
    k_up_add<<<(B_ * C_ * 256 + 255) / 256, 256, 0, stream>>>(fus1, proc0, up0t, 8, 8, 16, 16);
    {
        dim3 g(B_ * (C_ / 8));
        k_conv3x3_lds<0><<<g, 256, 0, stream>>>(up0t, fus_c1 + (size_t)C_ * C_ * 9,
                                                fus_bn1s + C_, fus_bn1b + C_,
                                                nullptr, rbh0, 16, 16);
        k_conv3x3_lds<1><<<g, 256, 0, stream>>>(rbh0, fus_c2 + (size_t)C_ * C_ * 9,
                                                fus_bn2s + C_, fus_bn2b + C_,
                                                up0t, fus0, 16, 16);
    }

    // ---- output head ----
    k_bn_gelu<<<(B_ * C_ * 256 + 255) / 256, 256, 0, stream>>>(fus0, op_bn0s, op_bn0b, hbuf, 256);
    {
        dim3 g(B_ * (C_ / 8));
        k_conv3x3_lds<2><<<g, 256, 0, stream>>>(hbuf, op_conv, op_bn1s, op_bn1b,
                                                x, (float*)d_out, 16, 16);
    }
    (void)in_sizes; (void)n_in; (void)out_size;
}

// Round 6
// 4370.653 us; speedup vs baseline: 12.1797x; 2.4723x over previous
//
#include <hip/hip_runtime.h>
#include <hip/hip_bf16.h>
#include <math.h>

// ---------------------------------------------------------------------------
// HMABottleneck: B=4, C=512, H=W=16, DI=1024, K=4 dirs, N=16 states, R=32
// Round 6: scan -> chunked LDS-staged version (kills L2-latency serialization;
// delta dot fused in, zero global loads in inner loop). Rest = round 5.
// ---------------------------------------------------------------------------

constexpr int B_  = 4;
constexpr int C_  = 512;
constexpr int DI_ = 1024;
constexpr int K_  = 4;
constexpr int N_  = 16;
constexpr int R_  = 32;
constexpr float BNS_ = 0.9999950000374997f;   // 1/sqrt(1+1e-5)

__device__ inline float geluf(float x) {
    return 0.5f * x * (1.0f + erff(x * 0.70710678118654752f));
}
__device__ inline float siluf(float x) {
    return x / (1.0f + expf(-x));
}
__device__ inline float softplusf(float x) {
    return fmaxf(x, 0.0f) + log1pf(expf(-fabsf(x)));
}

__device__ inline float blockReduceSum(float v, float* sd) {
    int tid = threadIdx.x;
    sd[tid] = v; __syncthreads();
    for (int s = blockDim.x / 2; s > 0; s >>= 1) {
        if (tid < s) sd[tid] += sd[tid + s];
        __syncthreads();
    }
    float r = sd[0]; __syncthreads();
    return r;
}

// --------------------------- LN over channels (NCHW -> (B*L, C)) -----------
__global__ void k_ln_nchw(const float* __restrict__ x, const float* __restrict__ w,
                          const float* __restrict__ b, float* __restrict__ out,
                          int L, float eps) {
    int row = blockIdx.x;            // b*L + l
    int bb = row / L, l = row % L;
    __shared__ float sd[256];
    __shared__ float srow[C_];
    const float* xp = x + (size_t)bb * C_ * L + l;
    float sum = 0.f;
    for (int c = threadIdx.x; c < C_; c += 256) { float v = xp[(size_t)c * L]; srow[c] = v; sum += v; }
    sum = blockReduceSum(sum, sd);
    float mu = sum / C_;
    float vs = 0.f;
    for (int c = threadIdx.x; c < C_; c += 256) { float d = srow[c] - mu; vs += d * d; }
    vs = blockReduceSum(vs, sd);
    float rstd = rsqrtf(vs / C_ + eps);
    float* op = out + (size_t)row * C_;
    for (int c = threadIdx.x; c < C_; c += 256) op[c] = (srow[c] - mu) * rstd * w[c] + b[c];
}

// --------------------------- tiled f32 GEMM: out = A (M,K) * Bw(N,K)^T -----
template <int EPI>
__global__ void k_gemm_nt(const float* __restrict__ A, const float* __restrict__ Bw,
                          float* __restrict__ Cout, int M, int Nn, int Kk,
                          const float* __restrict__ Res, int L) {
    const int BK = 16;
    __shared__ float As[BK][65];
    __shared__ float Bs[BK][65];
    int m0 = blockIdx.y * 64, n0 = blockIdx.x * 64;
    int tid = threadIdx.x;
    int tx = tid % 16, ty = tid / 16;
    float acc[4][4] = {};
    for (int k0 = 0; k0 < Kk; k0 += BK) {
        int mm = tid >> 2;
        int kk = (tid & 3) * 4;
        float4 va = *reinterpret_cast<const float4*>(A + (size_t)(m0 + mm) * Kk + k0 + kk);
        As[kk + 0][mm] = va.x; As[kk + 1][mm] = va.y; As[kk + 2][mm] = va.z; As[kk + 3][mm] = va.w;
        float4 vb = *reinterpret_cast<const float4*>(Bw + (size_t)(n0 + mm) * Kk + k0 + kk);
        Bs[kk + 0][mm] = vb.x; Bs[kk + 1][mm] = vb.y; Bs[kk + 2][mm] = vb.z; Bs[kk + 3][mm] = vb.w;
        __syncthreads();
#pragma unroll
        for (int k = 0; k < BK; ++k) {
            float a[4], b2[4];
#pragma unroll
            for (int i = 0; i < 4; i++) a[i] = As[k][ty + 16 * i];
#pragma unroll
            for (int j = 0; j < 4; j++) b2[j] = Bs[k][tx + 16 * j];
#pragma unroll
            for (int i = 0; i < 4; i++)
#pragma unroll
                for (int j = 0; j < 4; j++) acc[i][j] += a[i] * b2[j];
        }
        __syncthreads();
    }
#pragma unroll
    for (int i = 0; i < 4; i++) {
        int m = m0 + ty + 16 * i;
#pragma unroll
        for (int j = 0; j < 4; j++) {
            int n = n0 + tx + 16 * j;
            if (EPI == 0) {
                Cout[(size_t)m * Nn + n] = acc[i][j];
            } else {
                int bb = m / L, l = m % L;
                size_t o = ((size_t)bb * C_ + n) * L + l;
                Cout[o] = Res[o] + acc[i][j];
            }
        }
    }
}

// --------------------------- depthwise 3x3 (pad1) + bias + SiLU ------------
__global__ void k_dwconv_silu(const float* __restrict__ xz, const float* __restrict__ cw,
                              const float* __restrict__ cb, float* __restrict__ xm,
                              int H, int W) {
    int L = H * W;
    int idx = blockIdx.x * 256 + threadIdx.x;            // (b, l, d) d fastest
    int total = B_ * L * DI_;
    if (idx >= total) return;
    int d = idx % DI_; int t = idx / DI_; int l = t % L; int bb = t / L;
    int h = l / W, w = l % W;
    float acc = cb[d];
    const float* wp = cw + d * 9;
#pragma unroll
    for (int dy = 0; dy < 3; dy++) {
        int hh = h + dy - 1;
        if ((unsigned)hh >= (unsigned)H) continue;
#pragma unroll
        for (int dx = 0; dx < 3; dx++) {
            int ww = w + dx - 1;
            if ((unsigned)ww >= (unsigned)W) continue;
            acc += xz[((size_t)bb * L + hh * W + ww) * (2 * DI_) + d] * wp[dy * 3 + dx];
        }
    }
    xm[idx] = siluf(acc);
}

// map (k,l) -> source flat index in row-major (h*W+w) order
__device__ inline int dir_src(int k, int l, int H, int W, int L) {
    int ll = (k >= 2) ? (L - 1 - l) : l;
    return (k & 1) ? ((ll % H) * W + ll / H) : ll;
}

// --------------------------- x_dbl (LDS row staging, 64 thr/block) ---------
__global__ void k_xdbl(const float* __restrict__ xm, const float* __restrict__ xproj,
                       float* __restrict__ xdbl, int H, int W) {
    int L = H * W;
    int blk = blockIdx.x;            // (b,k,l)
    int l = blk % L; int t = blk / L; int k = t % K_; int bb = t / K_;
    int src = dir_src(k, l, H, W, L);
    __shared__ float row[DI_];
    const float* xp = xm + ((size_t)bb * L + src) * DI_;
    for (int d = threadIdx.x; d < DI_; d += 64) row[d] = xp[d];
    __syncthreads();
    const float* wp = xproj + ((size_t)k * 64 + threadIdx.x) * DI_;
    float acc = 0.f;
    for (int d = 0; d < DI_; d++) acc += row[d] * wp[d];
    xdbl[((size_t)(bb * K_ + k) * 64 + threadIdx.x) * L + l] = acc;
}

// --------------------------- fused delta + scan, LDS-chunked ---------------
// One lane per (b,k,d); 64-thread block covers one (b,k, d-group of 64).
// Per chunk of CH=32 steps: cooperatively stage the 64 x_dbl rows
// (32 dts + 16 B + 16 C) and the u values in LDS, then run the serial scan
// steps entirely from registers + LDS (zero global loads in inner loop).
__global__ void k_scan_lds(const float* __restrict__ xm, const float* __restrict__ xdbl,
                           const float* __restrict__ dtw, const float* __restrict__ dtb,
                           const float* __restrict__ Alog, const float* __restrict__ Dp,
                           float* __restrict__ part, int H, int W) {
    const int CH = 32;
    int L = H * W;
    int t = threadIdx.x;                 // 0..63
    int blk = blockIdx.x;                // (bb, k, dg)
    const int ndg = DI_ / 64;            // 16
    int dg = blk % ndg; int t2 = blk / ndg; int k = t2 % K_; int bb = t2 / K_;
    int d = dg * 64 + t;

    __shared__ float s_xd[64][CH + 1];   // +1 pad: conflict-free row writes
    __shared__ float s_u[CH][64];

    float wreg[R_];
    const float* wp = dtw + ((size_t)k * DI_ + d) * R_;
#pragma unroll
    for (int r = 0; r < R_; r++) wreg[r] = wp[r];
    float A[N_], h[N_];
    const float* al = Alog + ((size_t)k * DI_ + d) * N_;
#pragma unroll
    for (int n = 0; n < N_; n++) { A[n] = -expf(al[n]); h[n] = 0.f; }
    float Dv = Dp[k * DI_ + d];
    float bias = dtb[k * DI_ + d];

    const float* bc  = xdbl + (size_t)(bb * K_ + k) * 64 * L;
    const float* xmb = xm + (size_t)bb * L * DI_;
    float* yb = part + (size_t)(bb * K_ + k) * L * DI_ + d;

    for (int l0 = 0; l0 < L; l0 += CH) {
        int cs = min(CH, L - l0);        // 32, or 16 when L==16
        __syncthreads();                 // LDS reuse guard
        // stage x_dbl: thread t owns row t (contiguous in l -> float4 loads)
        {
            const float* rp = bc + (size_t)t * L + l0;
            for (int j = 0; j < cs; j += 4) {
                float4 v = *reinterpret_cast<const float4*>(rp + j);
                s_xd[t][j + 0] = v.x; s_xd[t][j + 1] = v.y;
                s_xd[t][j + 2] = v.z; s_xd[t][j + 3] = v.w;
            }
        }
        // stage u: per j one wave-coalesced load of 64 consecutive d
        for (int j = 0; j < cs; j++) {
            int src = dir_src(k, l0 + j, H, W, L);
            s_u[j][t] = xmb[(size_t)src * DI_ + d];
        }
        __syncthreads();
        for (int j = 0; j < cs; j++) {
            float acc = bias;
#pragma unroll
            for (int r = 0; r < R_; r++) acc += s_xd[r][j] * wreg[r];
            float dl = softplusf(acc);
            float u  = s_u[j][t];
            float du = dl * u;
            float y = 0.f;
#pragma unroll
            for (int n = 0; n < N_; n++) {
                h[n] = expf(dl * A[n]) * h[n] + du * s_xd[32 + n][j];
                y += h[n] * s_xd[48 + n][j];
            }
            int src = dir_src(k, l0 + j, H, W, L);
            yb[(size_t)src * DI_] = y + Dv * u;
        }
    }
}

// --------------------------- merge 4 direction partials --------------------
__global__ void k_merge4(const float* __restrict__ part, float* __restrict__ ybuf,
                         int L) {
    int idx = blockIdx.x * 256 + threadIdx.x;    // (b,l,d)
    int total = B_ * L * DI_;
    if (idx >= total) return;
    int d = idx % DI_; int t = idx / DI_; int l = t % L; int bb = t / L;
    size_t s = ((size_t)bb * K_ * L + l) * DI_ + d;
    float v = part[s] + part[s + (size_t)L * DI_] + part[s + (size_t)2 * L * DI_]
            + part[s + (size_t)3 * L * DI_];
    ybuf[idx] = v;
}

// --------------------------- LN(y) * silu(z) -> t (B*L, DI) ----------------
__global__ void k_ln_silu(const float* __restrict__ y, const float* __restrict__ xz,
                          const float* __restrict__ onw, const float* __restrict__ onb,
                          float* __restrict__ tout) {
    int row = blockIdx.x;            // b*L + l
    __shared__ float sd[256];
    __shared__ float srow[DI_];
    const float* yp = y + (size_t)row * DI_;
    float sum = 0.f;
    for (int d = threadIdx.x; d < DI_; d += 256) { float v = yp[d]; srow[d] = v; sum += v; }
    sum = blockReduceSum(sum, sd);
    float mu = sum / DI_;
    float vs = 0.f;
    for (int d = threadIdx.x; d < DI_; d += 256) { float dv = srow[d] - mu; vs += dv * dv; }
    vs = blockReduceSum(vs, sd);
    float rstd = rsqrtf(vs / DI_ + 1e-5f);
    const float* zp = xz + (size_t)row * 2 * DI_ + DI_;
    float* tp = tout + (size_t)row * DI_;
    for (int d = threadIdx.x; d < DI_; d += 256) {
        float zn = zp[d];
        tp[d] = ((srow[d] - mu) * rstd * onw[d] + onb[d]) * siluf(zn);
    }
}

// --------------------------- downsample: dw conv s2 + BN + GELU ------------
__global__ void k_dwconv_s2_bn_gelu(const float* __restrict__ x, const float* __restrict__ dw,
                                    const float* __restrict__ bns, const float* __restrict__ bnb,
                                    float* __restrict__ out, int Hi, int Wi) {
    int Ho = Hi / 2, Wo = Wi / 2;
    int idx = blockIdx.x * 256 + threadIdx.x;            // (b,c,ho,wo)
    int total = B_ * C_ * Ho * Wo;
    if (idx >= total) return;
    int wo = idx % Wo; int t = idx / Wo; int ho = t % Ho; t /= Ho; int c = t % C_; int bb = t / C_;
    float acc = 0.f;
    const float* xp = x + ((size_t)bb * C_ + c) * Hi * Wi;
    const float* wp = dw + c * 9;
#pragma unroll
    for (int dy = 0; dy < 3; dy++) {
        int ih = ho * 2 + dy - 1;
        if ((unsigned)ih >= (unsigned)Hi) continue;
#pragma unroll
        for (int dx = 0; dx < 3; dx++) {
            int iw = wo * 2 + dx - 1;
            if ((unsigned)iw >= (unsigned)Wi) continue;
            acc += xp[ih * Wi + iw] * wp[dy * 3 + dx];
        }
    }
    acc = acc * (bns[c] * BNS_) + bnb[c];
    out[idx] = geluf(acc);
}

// --------------------------- pointwise 1x1 conv + BN + GELU ----------------
__global__ void k_pwconv_bn_gelu(const float* __restrict__ x, const float* __restrict__ pw,
                                 const float* __restrict__ bns, const float* __restrict__ bnb,
                                 float* __restrict__ out, int L) {
    int idx = blockIdx.x * 256 + threadIdx.x;            // (b,co,l)
    int total = B_ * C_ * L;
    if (idx >= total) return;
    int l = idx % L; int t = idx / L; int co = t % C_; int bb = t / C_;
    const float* xp = x + (size_t)bb * C_ * L + l;
    const float* wp = pw + (size_t)co * C_;
    float acc = 0.f;
    for (int ci = 0; ci < C_; ci++) acc += xp[(size_t)ci * L] * wp[ci];
    acc = acc * (bns[co] * BNS_) + bnb[co];
    out[idx] = geluf(acc);
}

// --------------------------- 3x3 conv, LDS plane staging -------------------
template <int MODE>
__global__ void k_conv3x3_lds(const float* __restrict__ x, const float* __restrict__ wgt,
                              const float* __restrict__ bns, const float* __restrict__ bnb,
                              const float* __restrict__ res, float* __restrict__ out,
                              int H, int W) {
    const int COB = 8;
    int L = H * W;
    int t = threadIdx.x;
    int h = t / W, w = t % W;
    int blk = blockIdx.x;
    int ng = C_ / COB;
    int cg = blk % ng; int bb = blk / ng;
    int co0 = cg * COB;
    __shared__ float plane[2][257];
    float acc[COB];
#pragma unroll
    for (int j = 0; j < COB; j++) acc[j] = 0.f;
    const float* xb = x + (size_t)bb * C_ * L;
    int p = 0;
    for (int ci = 0; ci < C_; ci++) {
        plane[p][t] = xb[(size_t)ci * L + t];
        __syncthreads();
        float v[9];
#pragma unroll
        for (int dy = 0; dy < 3; dy++) {
            int hh = h + dy - 1;
            bool hok = (unsigned)hh < (unsigned)H;
#pragma unroll
            for (int dx = 0; dx < 3; dx++) {
                int ww = w + dx - 1;
                bool ok = hok && ((unsigned)ww < (unsigned)W);
                v[dy * 3 + dx] = ok ? plane[p][hh * W + ww] : 0.f;
            }
        }
        const float* wr = wgt + ((size_t)co0 * C_ + ci) * 9;
#pragma unroll
        for (int j = 0; j < COB; j++) {
            const float* wj = wr + (size_t)j * C_ * 9;
            float a = acc[j];
#pragma unroll
            for (int q = 0; q < 9; q++) a += v[q] * wj[q];
            acc[j] = a;
        }
        p ^= 1;
    }
#pragma unroll
    for (int j = 0; j < COB; j++) {
        int co = co0 + j;
        float a = acc[j] * (bns[co] * BNS_) + bnb[co];
        size_t o = (((size_t)bb * C_ + co) * H + h) * W + w;
        if (MODE == 0) out[o] = geluf(a);
        else if (MODE == 1) out[o] = geluf(a + res[o]);
        else out[o] = geluf(a) + res[o];
    }
}

// --------------------------- bilinear up + skip add ------------------------
__global__ void k_up_add(const float* __restrict__ low, const float* __restrict__ skip,
                         float* __restrict__ out, int Hi, int Wi, int Ho, int Wo) {
    int idx = blockIdx.x * 256 + threadIdx.x;            // (b,c,ho,wo)
    int total = B_ * C_ * Ho * Wo;
    if (idx >= total) return;
    int wo = idx % Wo; int t = idx / Wo; int ho = t % Ho; t /= Ho; int c = t % C_; int bb = t / C_;
    float fy = (float)ho * (float)(Hi - 1) / (float)(Ho - 1);
    float fx = (float)wo * (float)(Wi - 1) / (float)(Wo - 1);
    int y0 = (int)floorf(fy); int y1 = min(y0 + 1, Hi - 1); float wy = fy - (float)y0;
    int x0 = (int)floorf(fx); int x1 = min(x0 + 1, Wi - 1); float wx = fx - (float)x0;
    const float* lp = low + ((size_t)bb * C_ + c) * Hi * Wi;
    float g0 = lp[y0 * Wi + x0] * (1.f - wy) + lp[y1 * Wi + x0] * wy;
    float g1 = lp[y0 * Wi + x1] * (1.f - wy) + lp[y1 * Wi + x1] * wy;
    out[idx] = skip[idx] + g0 * (1.f - wx) + g1 * wx;
}

// --------------------------- BN + GELU elementwise -------------------------
__global__ void k_bn_gelu(const float* __restrict__ x, const float* __restrict__ s,
                          const float* __restrict__ b, float* __restrict__ out, int L) {
    int idx = blockIdx.x * 256 + threadIdx.x;            // (b,c,l)
    int total = B_ * C_ * L;
    if (idx >= total) return;
    int t = idx / L; int c = t % C_;
    out[idx] = geluf(x[idx] * (s[c] * BNS_) + b[c]);
}

// --------------------------- diagnostic fill (f32) -------------------------
__global__ void k_fill_out(float* o, int n, float v) {
    int i = blockIdx.x * 256 + threadIdx.x;
    if (i < n) o[i] = v;
}

// ===========================================================================
struct VssW {
    const float *lnw, *lnb, *inproj, *convw, *convb, *xproj, *dtw, *dtb, *Alog, *D, *onw, *onb, *outproj;
};

static void run_vss(const float* xc_in, float* xc_out, const VssW& p, int H, int W,
                    float* xln, float* xz, float* xm, float* xdbl,
                    float* part, float* ybuf, float* tbuf, hipStream_t stream) {
    int L = H * W, M = B_ * L;
    k_ln_nchw<<<M, 256, 0, stream>>>(xc_in, p.lnw, p.lnb, xln, L, 1e-6f);
    {
        dim3 g(2 * DI_ / 64, M / 64);
        k_gemm_nt<0><<<g, 256, 0, stream>>>(xln, p.inproj, xz, M, 2 * DI_, C_, nullptr, L);
    }
    {
        int tot = B_ * L * DI_;
        k_dwconv_silu<<<(tot + 255) / 256, 256, 0, stream>>>(xz, p.convw, p.convb, xm, H, W);
    }
    k_xdbl<<<B_ * K_ * L, 64, 0, stream>>>(xm, p.xproj, xdbl, H, W);
    k_scan_lds<<<B_ * K_ * (DI_ / 64), 64, 0, stream>>>(
        xm, xdbl, p.dtw, p.dtb, p.Alog, p.D, part, H, W);
    {
        int tot = B_ * L * DI_;
        k_merge4<<<(tot + 255) / 256, 256, 0, stream>>>(part, ybuf, L);
    }
    k_ln_silu<<<M, 256, 0, stream>>>(ybuf, xz, p.onw, p.onb, tbuf);
    {
        dim3 g(C_ / 64, M / 64);
        k_gemm_nt<1><<<g, 256, 0, stream>>>(tbuf, p.outproj, xc_out, M, C_, DI_, xc_in, L);
    }
}

extern "C" void kernel_launch(void* const* d_in, const int* in_sizes, int n_in,
                              void* d_out, int out_size, void* d_ws, size_t ws_size,
                              hipStream_t stream) {
    constexpr size_t NEED_FLOATS = 11075584;
    constexpr size_t NEED_BYTES  = NEED_FLOATS * 4;   // 44,302,336
    if (ws_size < NEED_BYTES) {
        k_fill_out<<<(out_size + 255) / 256, 256, 0, stream>>>((float*)d_out, out_size, 0.0f);
        return;
    }

    const float* x        = (const float*)d_in[0];
    const float* lnw      = (const float*)d_in[1];
    const float* lnb      = (const float*)d_in[2];
    const float* inproj   = (const float*)d_in[3];
    const float* convw    = (const float*)d_in[4];
    const float* convb    = (const float*)d_in[5];
    const float* xprojp   = (const float*)d_in[6];
    const float* dtwp     = (const float*)d_in[7];
    const float* dtbp     = (const float*)d_in[8];
    const float* Alogp    = (const float*)d_in[9];
    const float* Dpp      = (const float*)d_in[10];
    const float* onwp     = (const float*)d_in[11];
    const float* onbp     = (const float*)d_in[12];
    const float* outprojp = (const float*)d_in[13];
    const float* ds_dw    = (const float*)d_in[14];
    const float* ds_bn1s  = (const float*)d_in[15];
    const float* ds_bn1b  = (const float*)d_in[16];
    const float* ds_pw    = (const float*)d_in[17];
    const float* ds_bn2s  = (const float*)d_in[18];
    const float* ds_bn2b  = (const float*)d_in[19];
    const float* fus_c1   = (const float*)d_in[20];
    const float* fus_bn1s = (const float*)d_in[21];
    const float* fus_bn1b = (const float*)d_in[22];
    const float* fus_c2   = (const float*)d_in[23];
    const float* fus_bn2s = (const float*)d_in[24];
    const float* fus_bn2b = (const float*)d_in[25];
    const float* op_bn0s  = (const float*)d_in[26];
    const float* op_bn0b  = (const float*)d_in[27];
    const float* op_conv  = (const float*)d_in[28];
    const float* op_bn1s  = (const float*)d_in[29];
    const float* op_bn1b  = (const float*)d_in[30];

    float* ws = (float*)d_ws;
    float* xln   = ws;                    // 524288
    float* xz    = ws + 524288;           // 2097152
    float* xm    = ws + 2621440;          // 1048576
    float* xdbl  = ws + 3670016;          // 262144
    float* ybuf  = ws + 3932160;          // 1048576
    float* part  = ws + 4980736;          // 4194304
    float* tbuf  = part;                  // alias: part dead before ln_silu
    float* t_a   = ws + 9175040;          // 524288
    float* xr    = ws + 9699328;          // 524288
    float* p1    = ws + 10223616;         // 131072
    float* p2    = ws + 10354688;         // 32768
    float* proc0 = ws + 10387456;         // 524288
    float* proc1 = ws + 10911744;         // 131072
    float* proc2 = ws + 11042816;         // 32768
    float* p1pre = xz;                    // 131072
    float* p2pre = xz + 131072;           // 32768
    float* up1t  = xln;                   // 131072
    float* rbh1  = xln + 131072;          // 131072
    float* fus1  = xln + 262144;          // 131072
    float* up0t  = xm;                    // 524288
    float* rbh0  = part;                  // 524288
    float* fus0  = part + 524288;         // 524288
    float* hbuf  = part + 1048576;        // 524288

    VssW vp[5];
    for (int i = 0; i < 5; i++) {
        vp[i].lnw     = lnw + (size_t)i * C_;
        vp[i].lnb     = lnb + (size_t)i * C_;
        vp[i].inproj  = inproj + (size_t)i * 2 * DI_ * C_;
        vp[i].convw   = convw + (size_t)i * DI_ * 9;
        vp[i].convb   = convb + (size_t)i * DI_;
        vp[i].xproj   = xprojp + (size_t)i * K_ * 64 * DI_;
        vp[i].dtw     = dtwp + (size_t)i * K_ * DI_ * R_;
        vp[i].dtb     = dtbp + (size_t)i * K_ * DI_;
        vp[i].Alog    = Alogp + (size_t)i * K_ * DI_ * N_;
        vp[i].D       = Dpp + (size_t)i * K_ * DI_;
        vp[i].onw     = onwp + (size_t)i * DI_;
        vp[i].onb     = onbp + (size_t)i * DI_;
        vp[i].outproj = outprojp + (size_t)i * C_ * DI_;
    }

    // ---- stem: two VSS at 16x16 ----
    run_vss(x,   t_a, vp[0], 16, 16, xln, xz, xm, xdbl, part, ybuf, tbuf, stream);
    run_vss(t_a, xr,  vp[1], 16, 16, xln, xz, xm, xdbl, part, ybuf, tbuf, stream);

    // ---- down 0: 16 -> 8 ----
    k_dwconv_s2_bn_gelu<<<(B_ * C_ * 64 + 255) / 256, 256, 0, stream>>>(
        xr, ds_dw, ds_bn1s, ds_bn1b, p1pre, 16, 16);
    k_pwconv_bn_gelu<<<(B_ * C_ * 64 + 255) / 256, 256, 0, stream>>>(
        p1pre, ds_pw, ds_bn2s, ds_bn2b, p1, 64);
    // ---- down 1: 8 -> 4 ----
    k_dwconv_s2_bn_gelu<<<(B_ * C_ * 16 + 255) / 256, 256, 0, stream>>>(
        p1, ds_dw + (size_t)C_ * 9, ds_bn1s + C_, ds_bn1b + C_, p2pre, 8, 8);
    k_pwconv_bn_gelu<<<(B_ * C_ * 16 + 255) / 256, 256, 0, stream>>>(
        p2pre, ds_pw + (size_t)C_ * C_, ds_bn2s + C_, ds_bn2b + C_, p2, 16);

    // ---- per-scale VSS ----
    run_vss(xr, proc0, vp[2], 16, 16, xln, xz, xm, xdbl, part, ybuf, tbuf, stream);
    run_vss(p1, proc1, vp[3],  8,  8, xln, xz, xm, xdbl, part, ybuf, tbuf, stream);
    run_vss(p2, proc2, vp[4],  4,  4, xln, xz, xm, xdbl, part, ybuf, tbuf, stream);

    // ---- fuse i=1: up(proc2: 4->8) + proc1, resblk j=0 ----
    k_up_add<<<(B_ * C_ * 64 + 255) / 256, 256, 0, stream>>>(proc2, proc1, up1t, 4, 4, 8, 8);
    {
        dim3 g(B_ * (C_ / 8));
        k_conv3x3_lds<0><<<g, 64, 0, stream>>>(up1t, fus_c1, fus_bn1s, fus_bn1b,
                                               nullptr, rbh1, 8, 8);
        k_conv3x3_lds<1><<<g, 64, 0, stream>>>(rbh1, fus_c2, fus_bn2s, fus_bn2b,
                                               up1t, fus1, 8, 8);
    }
    // ---- fuse i=0: up(fus1: 8->16) + proc0, resblk j=1 ----
    k_up_add<<<(B_ * C_ * 256 + 255) / 256, 256, 0, stream>>>(fus1, proc0, up0t, 8, 8, 16, 16);
    {
        dim3 g(B_ * (C_ / 8));
        k_conv3x3_lds<0><<<g, 256, 0, stream>>>(up0t, fus_c1 + (size_t)C_ * C_ * 9,
                                                fus_bn1s + C_, fus_bn1b + C_,
                                                nullptr, rbh0, 16, 16);
        k_conv3x3_lds<1><<<g, 256, 0, stream>>>(rbh0, fus_c2 + (size_t)C_ * C_ * 9,
                                                fus_bn2s + C_, fus_bn2b + C_,
                                                up0t, fus0, 16, 16);
    }

    // ---- output head ----
    k_bn_gelu<<<(B_ * C_ * 256 + 255) / 256, 256, 0, stream>>>(fus0, op_bn0s, op_bn0b, hbuf, 256);
    {
        dim3 g(B_ * (C_ / 8));
        k_conv3x3_lds<2><<<g, 256, 0, stream>>>(hbuf, op_conv, op_bn1s, op_bn1b,
                                                x, (float*)d_out, 16, 16);
    }
    (void)in_sizes; (void)n_in; (void)out_size;
}